// Round 1
// 292.367 us; speedup vs baseline: 1.0059x; 1.0059x over previous
//
#include <hip/hip_runtime.h>
#include <hip/hip_bf16.h>

#define UHG_EPS 1e-9
#define ZDIM 128

#define EDGE_BLOCKS 1024
#define NODE_BLOCKS 1024
#define BLOCK 256

// ws layout:
//   [0      , 16 KB) : double prox partials (one per edge block)
//   [16 KB  , 24 KB) : double comp partials (one per node block)
//   [24 KB  , ...  ) : float2 table[N] (compact x,y per node)
#define PROX_OFF 0
#define COMP_OFF (16 * 1024)
#define TABLE_OFF (24 * 1024)

// native clang vector types (HIP_vector_type is rejected by cache-control builtins)
typedef float vfloat2 __attribute__((ext_vector_type(2)));
typedef int vint4 __attribute__((ext_vector_type(4)));

// CK-style asm-declared buffer load: rsrc, voffset(bytes), soffset, cachepolicy.
// cachepolicy bit0 = SC0 on gfx950: agent-scope read -> L1 bypass, L2 allocate.
__device__ vfloat2 llvm_amdgcn_raw_buffer_load_v2f32(vint4 rsrc, int voffset, int soffset,
                                                     int cpol) __asm("llvm.amdgcn.raw.buffer.load.v2f32");

__device__ __forceinline__ vint4 make_srd(const void* base, unsigned int bytes) {
    union { const void* p; unsigned int w[2]; } pb;
    pb.p = base;
    vint4 r;
    r.x = (int)pb.w[0];
    r.y = (int)pb.w[1];          // base[47:32], stride=0
    r.z = (int)bytes;            // num_records in bytes (stride==0)
    r.w = 0x00020000;            // raw dword access
    return r;
}

// ---------------- device helpers ----------------

__device__ __forceinline__ double safe_den(double den) {
    return copysign(fmax(fabs(den), UHG_EPS), den);
}

__device__ __forceinline__ double quad_xy(vfloat2 a, vfloat2 b) {
    double xa = a.x, ya = a.y, xb = b.x, yb = b.y;
    double aa = 1.0 - (xa * xa + ya * ya);
    double bb = 1.0 - (xb * xb + yb * yb);
    double ab = 1.0 - (xa * xb + ya * yb);
    double den = aa * bb;
    double num = ab * ab - den;
    return num / safe_den(den);
}

// Block reduction: returns total on thread 0. sh must hold >= 8 doubles.
__device__ __forceinline__ double block_reduce(double v, double* sh) {
    int lane = threadIdx.x & 63;
    int wid = threadIdx.x >> 6;
    v += __shfl_down(v, 32);
    v += __shfl_down(v, 16);
    v += __shfl_down(v, 8);
    v += __shfl_down(v, 4);
    v += __shfl_down(v, 2);
    v += __shfl_down(v, 1);
    if (lane == 0) sh[wid] = v;
    __syncthreads();
    double r = 0.0;
    if (wid == 0) {
        int nw = blockDim.x >> 6;
        r = (lane < nw) ? sh[lane] : 0.0;
        r += __shfl_down(r, 4);
        r += __shfl_down(r, 2);
        r += __shfl_down(r, 1);
    }
    __syncthreads();
    return r;
}

// ---------------- kernels ----------------

// Build compact (x,y) table + compactness partials. Grid = NODE_BLOCKS fixed.
__global__ __launch_bounds__(BLOCK) void node_kernel(const float* __restrict__ z,
                                                     vfloat2* __restrict__ table,
                                                     double* __restrict__ comp_partials, int N) {
    __shared__ double sh[8];
    const vfloat2* zp = (const vfloat2*)z;
    double local = 0.0;
    for (int i = blockIdx.x * BLOCK + threadIdx.x; i < N; i += NODE_BLOCKS * BLOCK) {
        vfloat2 v = zp[(size_t)i * (ZDIM / 2)];
        if (table) table[i] = v;
        double x = v.x, y = v.y;
        double aa = 1.0 - (x * x + y * y);
        local += (1.0 - aa) / safe_den(aa);   // ab=1, bb=1 against origin
    }
    double tot = block_reduce(local, sh);
    if (threadIdx.x == 0) comp_partials[blockIdx.x] = tot;
}

// Proximity partials over all edges. Grid = EDGE_BLOCKS fixed (all co-resident).
// Random 8B table gathers are L2-hits; throughput = in-flight-requests / L2-latency
// (Little's law). The previous version kept ~16 requests in flight only ~40% of the
// time (zero outstanding during the arrival gap + FP64 math). This version software-
// pipelines the GATHERS one grid-stride iteration ahead: at the top of iteration k we
// issue stage k+1's 16 gathers (indices prefetched in iteration k-1), prefetch indices
// for k+2, then consume stage k. Each wave holds ~16 requests outstanding continuously.
// COMPACT=1: 8B table entries (voffset=id*8); COMPACT=0: gather from z rows (id*512).
#define GATHER8(dsta, i0, i1)                                                   \
    dsta[0] = llvm_amdgcn_raw_buffer_load_v2f32(srd, (i0).x << SHIFT, 0, 1);    \
    dsta[1] = llvm_amdgcn_raw_buffer_load_v2f32(srd, (i0).y << SHIFT, 0, 1);    \
    dsta[2] = llvm_amdgcn_raw_buffer_load_v2f32(srd, (i0).z << SHIFT, 0, 1);    \
    dsta[3] = llvm_amdgcn_raw_buffer_load_v2f32(srd, (i0).w << SHIFT, 0, 1);    \
    dsta[4] = llvm_amdgcn_raw_buffer_load_v2f32(srd, (i1).x << SHIFT, 0, 1);    \
    dsta[5] = llvm_amdgcn_raw_buffer_load_v2f32(srd, (i1).y << SHIFT, 0, 1);    \
    dsta[6] = llvm_amdgcn_raw_buffer_load_v2f32(srd, (i1).z << SHIFT, 0, 1);    \
    dsta[7] = llvm_amdgcn_raw_buffer_load_v2f32(srd, (i1).w << SHIFT, 0, 1);

template <int COMPACT>
__global__ __launch_bounds__(BLOCK) void edge_kernel(const vint4* __restrict__ src4,
                                                     const vint4* __restrict__ dst4, int nvec,
                                                     const int* __restrict__ src,
                                                     const int* __restrict__ dst, int E,
                                                     const void* __restrict__ xy, int N,
                                                     double* __restrict__ prox_partials) {
    __shared__ double sh[8];
    double local = 0.0;
    int tid = blockIdx.x * BLOCK + threadIdx.x;
    const int gstride = EDGE_BLOCKS * BLOCK;
    const int SHIFT = COMPACT ? 3 : 9;   // 8B entries vs 512B z-rows

    vint4 srd = make_srd(xy, COMPACT ? (unsigned int)N * 8u : (unsigned int)N * 512u);

    int nvec2 = nvec / 2;   // pairs of int4 (8 edges per thread-iteration)

    int v0 = tid;
    bool p0 = v0 < nvec2;
    int v1 = v0 + gstride;
    bool p1 = v1 < nvec2;

    vint4 is0 = {}, is1 = {}, id0 = {}, id1 = {};   // indices for next stage
    vfloat2 ca[8] = {}, cb[8] = {};                 // current stage data (in flight)
    vfloat2 na[8] = {}, nb[8] = {};                 // next stage data

    if (p0) {   // prologue: indices + gathers for stage 0
        vint4 s0 = __builtin_nontemporal_load(src4 + 2 * (long)v0);
        vint4 s1 = __builtin_nontemporal_load(src4 + 2 * (long)v0 + 1);
        vint4 d0 = __builtin_nontemporal_load(dst4 + 2 * (long)v0);
        vint4 d1 = __builtin_nontemporal_load(dst4 + 2 * (long)v0 + 1);
        GATHER8(ca, s0, s1);
        GATHER8(cb, d0, d1);
    }
    if (p1) {   // prologue: indices for stage 1
        is0 = __builtin_nontemporal_load(src4 + 2 * (long)v1);
        is1 = __builtin_nontemporal_load(src4 + 2 * (long)v1 + 1);
        id0 = __builtin_nontemporal_load(dst4 + 2 * (long)v1);
        id1 = __builtin_nontemporal_load(dst4 + 2 * (long)v1 + 1);
    }

    while (p0) {
        // 1) issue next stage's 16 gathers (keeps the miss queue full during math)
        if (p1) {
            GATHER8(na, is0, is1);
            GATHER8(nb, id0, id1);
        }
        // 2) prefetch indices two stages ahead (is*/id* regs are dead after step 1)
        int v2 = v1 + gstride;
        bool p2 = v2 < nvec2;
        if (p2) {
            is0 = __builtin_nontemporal_load(src4 + 2 * (long)v2);
            is1 = __builtin_nontemporal_load(src4 + 2 * (long)v2 + 1);
            id0 = __builtin_nontemporal_load(dst4 + 2 * (long)v2);
            id1 = __builtin_nontemporal_load(dst4 + 2 * (long)v2 + 1);
        }
        // pin: all loads above must be issued before the math below
        __builtin_amdgcn_sched_barrier(0);
        // 3) consume current stage (compiler waits only on ca/cb: vmcnt leaves
        //    the 20 loads issued above in flight)
#pragma unroll
        for (int i = 0; i < 8; ++i) local += quad_xy(ca[i], cb[i]);
        // 4) rotate stages (32 v_movs, negligible vs ~700-cycle math phase)
#pragma unroll
        for (int i = 0; i < 8; ++i) { ca[i] = na[i]; cb[i] = nb[i]; }
        p0 = p1;
        v1 = v2;
        p1 = p2;
    }

    // remainder edges (E not divisible by 8)
    for (int e = 8 * nvec2 + tid; e < E; e += gstride) {
        vfloat2 a = llvm_amdgcn_raw_buffer_load_v2f32(srd, src[e] << SHIFT, 0, 1);
        vfloat2 b = llvm_amdgcn_raw_buffer_load_v2f32(srd, dst[e] << SHIFT, 0, 1);
        local += quad_xy(a, b);
    }
    double tot = block_reduce(local, sh);
    if (threadIdx.x == 0) prox_partials[blockIdx.x] = tot;
}

// Sum partials + spread over first min(10,E) edges + combine. One block of 256.
__global__ __launch_bounds__(BLOCK) void finalize_kernel(const int* __restrict__ src,
                                                         const int* __restrict__ dst,
                                                         const float* __restrict__ z,
                                                         const double* __restrict__ prox_partials,
                                                         const double* __restrict__ comp_partials,
                                                         float* __restrict__ out, int N, int E) {
    __shared__ double sh[8];
    int t = threadIdx.x;

    double pl = 0.0;
    for (int i = t; i < EDGE_BLOCKS; i += BLOCK) pl += prox_partials[i];
    double prox = block_reduce(pl, sh);

    double cl = 0.0;
    for (int i = t; i < NODE_BLOCKS; i += BLOCK) cl += comp_partials[i];
    double comp = block_reduce(cl, sh);

    int n_sp = E < 10 ? E : 10;
    double sl = 0.0;
    if (t < n_sp) {
        int s = src[t], d = dst[t];
        double xa = z[(size_t)s * ZDIM], ya = z[(size_t)s * ZDIM + 1];
        double xb = z[(size_t)d * ZDIM], yb = z[(size_t)d * ZDIM + 1];
        // lines = cross(point, origin[0,0,1]) = (y, -x, 0)
        // uhg_inner(la,lb) = -(la_x*lb_x + la_y*lb_y) + 0
        double aa = -(ya * ya + xa * xa);
        double bb = -(yb * yb + xb * xb);
        double ab = -(ya * yb + xa * xb);
        double den = aa * bb;
        sl = (ab * ab - den) / safe_den(den);
    }
    double spread = block_reduce(sl, sh);

    if (t == 0) {
        double loss = prox / (double)E + comp / (double)N;
        if (n_sp > 0) loss += 0.1 * (spread / (double)n_sp);
        out[0] = (float)loss;
    }
}

// ---------------- launch ----------------

extern "C" void kernel_launch(void* const* d_in, const int* in_sizes, int n_in,
                              void* d_out, int out_size, void* d_ws, size_t ws_size,
                              hipStream_t stream) {
    const float* z = (const float*)d_in[0];
    const int* edge_index = (const int*)d_in[1];
    float* out = (float*)d_out;

    const int N = in_sizes[0] / ZDIM;
    const int E = in_sizes[1] / 2;
    const int* src = edge_index;
    const int* dst = edge_index + (size_t)E;

    double* prox_partials = (double*)((char*)d_ws + PROX_OFF);
    double* comp_partials = (double*)((char*)d_ws + COMP_OFF);
    vfloat2* table = (vfloat2*)((char*)d_ws + TABLE_OFF);
    bool use_table = ws_size >= TABLE_OFF + (size_t)N * sizeof(vfloat2);

    node_kernel<<<NODE_BLOCKS, BLOCK, 0, stream>>>(z, use_table ? table : nullptr,
                                                   comp_partials, N);

    int nvec = E / 4;
    if (use_table) {
        edge_kernel<1><<<EDGE_BLOCKS, BLOCK, 0, stream>>>((const vint4*)src, (const vint4*)dst,
                                                          nvec, src, dst, E, table, N,
                                                          prox_partials);
    } else {
        // correct fallback: gather x,y from the head of each 512B z row
        edge_kernel<0><<<EDGE_BLOCKS, BLOCK, 0, stream>>>((const vint4*)src, (const vint4*)dst,
                                                          nvec, src, dst, E, z, N,
                                                          prox_partials);
    }

    finalize_kernel<<<1, BLOCK, 0, stream>>>(src, dst, z, prox_partials, comp_partials,
                                             out, N, E);
}